// Round 12
// baseline (8415.331 us; speedup 1.0000x reference)
//
#include <hip/hip_runtime.h>

#define N_PTS 16384
#define ROWF  131        // 3 coords + 128 features
#define M_OUT 4096       // N / POOL
#define KNN   16
#define FPS_T 1024       // fps threads (16 waves)
#define SORT_T 1024

typedef unsigned long long u64;
typedef float f32x2 __attribute__((ext_vector_type(2)));

// spread 4 bits -> every 3rd bit (Morton interleave LUT)
__device__ __constant__ unsigned short c_spread4[16] =
  {0,1,8,9,64,65,72,73,512,513,520,521,576,577,584,585};

__device__ __forceinline__ int cell_of(float x, float y, float z) {
  int ix = (int)floorf((x + 4.0f) * 2.0f); ix = ix < 0 ? 0 : (ix > 15 ? 15 : ix);
  int iy = (int)floorf((y + 4.0f) * 2.0f); iy = iy < 0 ? 0 : (iy > 15 ? 15 : iy);
  int iz = (int)floorf((z + 4.0f) * 2.0f); iz = iz < 0 ? 0 : (iz > 15 ? 15 : iz);
  return (int)c_spread4[ix] | ((int)c_spread4[iy] << 1) | ((int)c_spread4[iz] << 2);
}

// DPP cross-lane helpers (VALU pipe). 'old' operand keeps own value where the
// dpp source is disabled (partial ROW_MASK) -- verified pattern from r10/r11.
template <int CTRL, int ROW_MASK>
__device__ __forceinline__ u64 kmax_dpp(u64 k) {
  const int lo = (int)(unsigned)k, hi = (int)(unsigned)(k >> 32);
  const int nlo = __builtin_amdgcn_update_dpp(lo, lo, CTRL, ROW_MASK, 0xf, false);
  const int nhi = __builtin_amdgcn_update_dpp(hi, hi, CTRL, ROW_MASK, 0xf, false);
  const u64 nk = ((u64)(unsigned)nhi << 32) | (unsigned)nlo;
  return nk > k ? nk : k;
}
template <int CTRL, int ROW_MASK>
__device__ __forceinline__ float fmax_dpp(float v) {
  const int p = __builtin_amdgcn_update_dpp(__float_as_int(v), __float_as_int(v),
                                            CTRL, ROW_MASK, 0xf, false);
  return fmaxf(v, __int_as_float(p));
}
template <int CTRL, int ROW_MASK>
__device__ __forceinline__ unsigned umin_dpp(unsigned v) {
  const unsigned p = (unsigned)__builtin_amdgcn_update_dpp((int)v, (int)v,
                                            CTRL, ROW_MASK, 0xf, false);
  return v < p ? v : p;
}

__device__ __forceinline__ float wave_fsum(float v) {
#pragma unroll
  for (int off = 32; off; off >>= 1) v += __shfl_xor(v, off);
  return v;   // bitwise-uniform: butterfly partners commute (a+b==b+a)
}
__device__ __forceinline__ float wave_fmax(float v) {
#pragma unroll
  for (int off = 32; off; off >>= 1) v = fmaxf(v, __shfl_xor(v, off));
  return v;
}
__device__ __forceinline__ float uni_f(float v) {   // force SGPR residency
  return __int_as_float(__builtin_amdgcn_readfirstlane(__float_as_int(v)));
}

// ---------------------------------------------------------------------------
// 1) Extract coords into packed float4 (x,y,z,unused), orig-index order.
// ---------------------------------------------------------------------------
__global__ void prep_kernel(const float* __restrict__ x,
                            float4* __restrict__ coords4) {
  const int p = blockIdx.x * blockDim.x + threadIdx.x;
  if (p < N_PTS) {
    coords4[p] = make_float4(x[p * ROWF + 0], x[p * ROWF + 1],
                             x[p * ROWF + 2], 0.0f);
  }
}

// ---------------------------------------------------------------------------
// 2) Counting-sort by Morton cell. NEW rank->slot map for the 4-group fps
//    layout: rank rk -> wave w=rk>>10, group g=(rk>>8)&3, lane l=(rk>>2)&63,
//    elem j=rk&3; load-elem i=g*4+j, thread t=w*64+l, slot=(i<<10)|t.
//    So group g of wave w = 256 CONSECUTIVE Morton ranks (compact region),
//    and fps init loads gP4[(i<<10)+tid] stay perfectly coalesced.
// ---------------------------------------------------------------------------
__global__ __launch_bounds__(1024, 1)
void sort_kernel(const float4* __restrict__ coords4, float4* __restrict__ gP4) {
  __shared__ unsigned int sh[4096];
  __shared__ unsigned int sws[16];
  const int tid = threadIdx.x, lane = tid & 63, wid = tid >> 6;

#pragma unroll
  for (int i = 0; i < 4; ++i) sh[tid * 4 + i] = 0;
  __syncthreads();

  int cel[16];
#pragma unroll
  for (int j = 0; j < 16; ++j) {
    const float4 v = coords4[tid + SORT_T * j];
    const int c = cell_of(v.x, v.y, v.z);
    cel[j] = c;
    atomicAdd(&sh[c], 1u);
  }
  __syncthreads();

  const unsigned h0 = sh[tid * 4 + 0], h1 = sh[tid * 4 + 1];
  const unsigned h2 = sh[tid * 4 + 2], h3 = sh[tid * 4 + 3];
  const unsigned tsum = h0 + h1 + h2 + h3;
  unsigned inc = tsum;
#pragma unroll
  for (int off = 1; off < 64; off <<= 1) {
    const unsigned v = __shfl_up(inc, off);
    if (lane >= off) inc += v;
  }
  if (lane == 63) sws[wid] = inc;
  __syncthreads();
  if (tid == 0) {
    unsigned run = 0;
#pragma unroll
    for (int w = 0; w < 16; ++w) { const unsigned t = sws[w]; sws[w] = run; run += t; }
  }
  __syncthreads();
  const unsigned base = sws[wid] + inc - tsum;
  sh[tid * 4 + 0] = base;
  sh[tid * 4 + 1] = base + h0;
  sh[tid * 4 + 2] = base + h0 + h1;
  sh[tid * 4 + 3] = base + h0 + h1 + h2;
  __syncthreads();

#pragma unroll
  for (int j = 0; j < 16; ++j) {
    const int p = tid + SORT_T * j;
    const float4 v = coords4[p];
    const unsigned rk = atomicAdd(&sh[cel[j]], 1u);
    const unsigned w = rk >> 10, g = (rk >> 8) & 3u,
                   l = (rk >> 2) & 63u, jj = rk & 3u;
    const int slot = (int)((((g << 2) | jj) << 10) | ((w << 6) | l));
    gP4[slot] = make_float4(v.x, v.y, v.z, __int_as_float(p));
  }
}

// ---------------------------------------------------------------------------
// 3) FPS v12: 4 groups/wave of 256 consecutive Morton ranks, each with a
//    UNIFORM single-sphere prune (readfirstlane scalar branch -- no ballot,
//    no exec-mask waste). Round-11 math: VALU = 2633 cyc/step == all-dirty
//    floor; old wave-OR footprint (~2sigma region + 0.6sigma inflation)
//    never skipped. Group footprint = 1sigma box + inflation -> real skips.
//    Dirty group: pk-pair update (4 pts/lane), group max via 6-level DPP
//    f32-max, tie idx via 4-elem scan + DPP u32-min, cached u64 group key;
//    group constants forced to SGPRs (uni_f). Skip => provably no member
//    fminf(md,d2) changes (same margins as rounds 4-11, absmax 0) AND the
//    winner's group always fails its test (dd <= gr^2 <= gthr) => no stale
//    winner. Wave key = max(gk0..3), lane63 -> parity LDS, ONE barrier,
//    cross-wave u64 DPP. Key=(md_bits<<32)|(16383-ni): max md, tie->low idx.
// ---------------------------------------------------------------------------
#define REP16(F) F(0) F(1) F(2) F(3) F(4) F(5) F(6) F(7) \
                 F(8) F(9) F(10) F(11) F(12) F(13) F(14) F(15)
#define REP8P(F) F(0,0,1) F(1,2,3) F(2,4,5) F(3,6,7) \
                 F(4,8,9) F(5,10,11) F(6,12,13) F(7,14,15)

__global__
__attribute__((amdgpu_flat_work_group_size(FPS_T, FPS_T)))
__attribute__((amdgpu_waves_per_eu(4, 4)))
void fps_kernel(const float4* __restrict__ coords4,
                const float4* __restrict__ gP4, float* __restrict__ out) {
#pragma clang fp contract(off)
  __shared__ u64 s_wkey[2][16];
  const int tid = threadIdx.x, lane = tid & 63, wid = tid >> 6;

#define FPS_DECLP(t,a,b) f32x2 PX##t, PY##t, PZ##t;
  REP8P(FPS_DECLP)
#undef FPS_DECLP
#define FPS_DECLS(j) float md##j; unsigned ni##j;
  REP16(FPS_DECLS)
#undef FPS_DECLS

#define FPS_INITP(t,a,b) {                                                 \
    const float4 va = gP4[(a << 10) + tid];                                \
    const float4 vb = gP4[(b << 10) + tid];                                \
    PX##t = (f32x2){va.x, vb.x};                                           \
    PY##t = (f32x2){va.y, vb.y};                                           \
    PZ##t = (f32x2){va.z, vb.z};                                           \
    ni##a = (unsigned)__float_as_int(va.w);                                \
    ni##b = (unsigned)__float_as_int(vb.w);                                \
    md##a = __int_as_float(0x7f800000);                                    \
    md##b = __int_as_float(0x7f800000); }
  REP8P(FPS_INITP)
#undef FPS_INITP

  // group constants (wave-uniform; forced to SGPRs via uni_f)
#define GDECL(g) float gcx##g, gcy##g, gcz##g, gr##g, gthr##g; u64 gk##g;
  GDECL(0) GDECL(1) GDECL(2) GDECL(3)
#undef GDECL

  // group g holds pairs (2g,2g+1) = elems 4g..4g+3 (256 consecutive ranks)
#define GINIT(g, tA, tB) {                                                 \
    const float sx = wave_fsum(PX##tA.x + PX##tA.y + PX##tB.x + PX##tB.y); \
    const float sy = wave_fsum(PY##tA.x + PY##tA.y + PY##tB.x + PY##tB.y); \
    const float sz = wave_fsum(PZ##tA.x + PZ##tA.y + PZ##tB.x + PZ##tB.y); \
    gcx##g = uni_f(sx * (1.0f / 256.0f));                                  \
    gcy##g = uni_f(sy * (1.0f / 256.0f));                                  \
    gcz##g = uni_f(sz * (1.0f / 256.0f));                                  \
    float r2 = 0.f;                                                        \
    { const float dx = PX##tA.x - gcx##g, dy = PY##tA.x - gcy##g,          \
                  dz = PZ##tA.x - gcz##g;                                  \
      r2 = fmaxf(r2, dx * dx + dy * dy + dz * dz); }                       \
    { const float dx = PX##tA.y - gcx##g, dy = PY##tA.y - gcy##g,          \
                  dz = PZ##tA.y - gcz##g;                                  \
      r2 = fmaxf(r2, dx * dx + dy * dy + dz * dz); }                       \
    { const float dx = PX##tB.x - gcx##g, dy = PY##tB.x - gcy##g,          \
                  dz = PZ##tB.x - gcz##g;                                  \
      r2 = fmaxf(r2, dx * dx + dy * dy + dz * dz); }                       \
    { const float dx = PX##tB.y - gcx##g, dy = PY##tB.y - gcy##g,          \
                  dz = PZ##tB.y - gcz##g;                                  \
      r2 = fmaxf(r2, dx * dx + dy * dy + dz * dz); }                       \
    r2 = wave_fmax(r2);                                                    \
    gr##g   = uni_f(sqrtf(r2) * 1.000001f + 1e-6f);                        \
    gthr##g = uni_f(__int_as_float(0x7f800000));                           \
    gk##g   = 0; }
  GINIT(0, 0, 1) GINIT(1, 2, 3) GINIT(2, 4, 5) GINIT(3, 6, 7)
#undef GINIT

  u64 wkk = 0;                             // cached wave max key
  const float4 q0 = coords4[0];
  float qx = q0.x, qy = q0.y, qz = q0.z;
  if (tid == 0) { out[0] = qx; out[1] = qy; out[2] = qz; }

  for (int s = 1; s < M_OUT; ++s) {
    const f32x2 QX = {qx, qx}, QY = {qy, qy}, QZ = {qz, qz};
    bool any = false;

#define GSTEP(g, tA, tB, e0, e1, e2, e3) {                                 \
    const float ddx = qx - gcx##g, ddy = qy - gcy##g, ddz = qz - gcz##g;   \
    const float dd = ddx * ddx + ddy * ddy + ddz * ddz;                    \
    if (__builtin_amdgcn_readfirstlane(                                    \
            (int)(dd * 0.999999f <= gthr##g))) {                          \
      any = true;                                                          \
      const f32x2 dxA = PX##tA - QX, dyA = PY##tA - QY, dzA = PZ##tA - QZ; \
      const f32x2 xxA = dxA * dxA, yyA = dyA * dyA, zzA = dzA * dzA;       \
      const f32x2 d2A = (xxA + yyA) + zzA;                                 \
      const f32x2 dxB = PX##tB - QX, dyB = PY##tB - QY, dzB = PZ##tB - QZ; \
      const f32x2 xxB = dxB * dxB, yyB = dyB * dyB, zzB = dzB * dzB;       \
      const f32x2 d2B = (xxB + yyB) + zzB;                                 \
      const float n0 = fminf(md##e0, d2A.x); md##e0 = n0;                  \
      const float n1 = fminf(md##e1, d2A.y); md##e1 = n1;                  \
      const float n2 = fminf(md##e2, d2B.x); md##e2 = n2;                  \
      const float n3 = fminf(md##e3, d2B.y); md##e3 = n3;                  \
      float gm = fmaxf(fmaxf(n0, n1), fmaxf(n2, n3));                      \
      gm = fmax_dpp<0xB1,  0xf>(gm);                                       \
      gm = fmax_dpp<0x4E,  0xf>(gm);                                       \
      gm = fmax_dpp<0x141, 0xf>(gm);                                       \
      gm = fmax_dpp<0x140, 0xf>(gm);                                       \
      gm = fmax_dpp<0x142, 0xa>(gm);                                       \
      gm = fmax_dpp<0x143, 0xc>(gm);                                       \
      const float gmu = __int_as_float(                                    \
          __builtin_amdgcn_readlane(__float_as_int(gm), 63));              \
      unsigned c = 0xFFFFFFFFu;                                            \
      c = (md##e0 == gmu) ? (ni##e0 < c ? ni##e0 : c) : c;                 \
      c = (md##e1 == gmu) ? (ni##e1 < c ? ni##e1 : c) : c;                 \
      c = (md##e2 == gmu) ? (ni##e2 < c ? ni##e2 : c) : c;                 \
      c = (md##e3 == gmu) ? (ni##e3 < c ? ni##e3 : c) : c;                 \
      c = umin_dpp<0xB1,  0xf>(c);                                         \
      c = umin_dpp<0x4E,  0xf>(c);                                         \
      c = umin_dpp<0x141, 0xf>(c);                                         \
      c = umin_dpp<0x140, 0xf>(c);                                         \
      c = umin_dpp<0x142, 0xa>(c);                                         \
      c = umin_dpp<0x143, 0xc>(c);                                         \
      const unsigned cu = (unsigned)__builtin_amdgcn_readlane((int)c, 63); \
      gk##g = ((u64)__float_as_uint(gmu) << 32) |                          \
              (unsigned)(N_PTS - 1 - cu);                                  \
      const float uu = (gr##g + sqrtf(gmu * 1.0001f)) * 1.000003f;         \
      gthr##g = uni_f(uu * uu * 1.000001f);                                \
    } }
    GSTEP(0, 0, 1,  0,  1,  2,  3)
    GSTEP(1, 2, 3,  4,  5,  6,  7)
    GSTEP(2, 4, 5,  8,  9, 10, 11)
    GSTEP(3, 6, 7, 12, 13, 14, 15)
#undef GSTEP

    if (any) {                                   // uniform
      u64 w = gk0;
      w = (gk1 > w) ? gk1 : w;
      w = (gk2 > w) ? gk2 : w;
      w = (gk3 > w) ? gk3 : w;
      wkk = w;
    }

    const int par = s & 1;
    if (lane == 63) s_wkey[par][wid] = wkk;
    __syncthreads();                             // the ONLY barrier per step
    u64 kk = s_wkey[par][lane & 15];
    kk = kmax_dpp<0xB1,  0xf>(kk);
    kk = kmax_dpp<0x4E,  0xf>(kk);
    kk = kmax_dpp<0x141, 0xf>(kk);
    kk = kmax_dpp<0x140, 0xf>(kk);               // all lanes: block max

    const int oidx = (N_PTS - 1) - (int)(unsigned)(kk & 0xFFFFFFFFu);
    const float4 wpt = coords4[oidx];            // one uniform 16B load
    qx = wpt.x; qy = wpt.y; qz = wpt.z;
    if (tid == 0) {
      float* orow = out + (size_t)s * ROWF;
      orow[0] = qx; orow[1] = qy; orow[2] = qz;
    }
  }
}

// ---------------------------------------------------------------------------
// 4) KNN top-16 (ties -> lowest index) fused with feature max-pool.
// ---------------------------------------------------------------------------
__global__ __launch_bounds__(256)
void knn_pool_kernel(const float* __restrict__ x,
                     const float4* __restrict__ coords4,
                     float* __restrict__ out) {
  const int lane = threadIdx.x & 63;
  const int q = blockIdx.x * 4 + (threadIdx.x >> 6);

  const float qx = out[(size_t)q * ROWF + 0];
  const float qy = out[(size_t)q * ROWF + 1];
  const float qz = out[(size_t)q * ROWF + 2];

  u64 h[KNN];
#pragma unroll
  for (int k = 0; k < KNN; ++k) h[k] = ~0ULL;

  for (int c = lane; c < N_PTS; c += 64) {
    const float4 v = coords4[c];                 // coalesced 16B
    const float dx = v.x - qx, dy = v.y - qy, dz = v.z - qz;
    const float d2 = __fadd_rn(__fadd_rn(__fmul_rn(dx, dx), __fmul_rn(dy, dy)),
                               __fmul_rn(dz, dz));
    const u64 e = ((u64)__float_as_uint(d2) << 32) | (unsigned)c;
    if (e < h[KNN - 1]) {
#pragma unroll
      for (int k = KNN - 1; k >= 1; --k) {
        const u64 prev = h[k - 1];
        h[k] = (e < prev) ? prev : ((e < h[k]) ? e : h[k]);
      }
      h[0] = (e < h[0]) ? e : h[0];
    }
  }

  int nbr[KNN];
#pragma unroll
  for (int rr = 0; rr < KNN; ++rr) {
    u64 best = h[0];
#pragma unroll
    for (int off = 32; off; off >>= 1) {
      const u64 o = __shfl_xor(best, off);
      best = (o < best) ? o : best;
    }
    nbr[rr] = (int)(unsigned)(best & 0xffffffffULL);
    if (h[0] == best) {
#pragma unroll
      for (int k = 0; k < KNN - 1; ++k) h[k] = h[k + 1];
      h[KNN - 1] = ~0ULL;
    }
  }

  float a0 = __int_as_float(0xff800000), a1 = a0;
#pragma unroll
  for (int rr = 0; rr < KNN; ++rr) {
    const float* row = x + (size_t)nbr[rr] * ROWF + 3;
    a0 = fmaxf(a0, row[lane]);
    a1 = fmaxf(a1, row[lane + 64]);
  }
  float* orow = out + (size_t)q * ROWF + 3;
  orow[lane] = a0;
  orow[lane + 64] = a1;
}

extern "C" void kernel_launch(void* const* d_in, const int* in_sizes, int n_in,
                              void* d_out, int out_size, void* d_ws, size_t ws_size,
                              hipStream_t stream) {
  const float* x = (const float*)d_in[0];
  float* out = (float*)d_out;

  float4* coords4 = (float4*)d_ws;          // N float4 (256 KB)
  float4* gP4     = coords4 + N_PTS;        // N float4 (256 KB)

  hipLaunchKernelGGL(prep_kernel, dim3(64), dim3(256), 0, stream, x, coords4);
  hipLaunchKernelGGL(sort_kernel, dim3(1), dim3(1024), 0, stream, coords4, gP4);
  hipLaunchKernelGGL(fps_kernel, dim3(1), dim3(FPS_T), 0, stream,
                     coords4, gP4, out);
  hipLaunchKernelGGL(knn_pool_kernel, dim3(M_OUT / 4), dim3(256), 0, stream,
                     x, coords4, out);
}

// Round 13
// 6651.471 us; speedup vs baseline: 1.2652x; 1.2652x over previous
//
#include <hip/hip_runtime.h>

#define N_PTS 16384
#define ROWF  131        // 3 coords + 128 features
#define M_OUT 4096       // N / POOL
#define KNN   16
#define FPS_T 1024       // fps threads (16 waves)

typedef unsigned long long u64;
typedef float f32x2 __attribute__((ext_vector_type(2)));

// u64 max-combine with a DPP-moved partner (VALU pipe, ~2cyc vs ~50cyc shfl).
// Verified on-device in rounds 10-12 (absmax 0 throughout).
template <int CTRL, int ROW_MASK>
__device__ __forceinline__ u64 kmax_dpp(u64 k) {
  const int lo = (int)(unsigned)k, hi = (int)(unsigned)(k >> 32);
  const int nlo = __builtin_amdgcn_update_dpp(lo, lo, CTRL, ROW_MASK, 0xf, false);
  const int nhi = __builtin_amdgcn_update_dpp(hi, hi, CTRL, ROW_MASK, 0xf, false);
  const u64 nk = ((u64)(unsigned)nhi << 32) | (unsigned)nlo;
  return nk > k ? nk : k;
}

// ---------------------------------------------------------------------------
// 1) Extract coords into packed float4 (x,y,z,0), original index order.
// ---------------------------------------------------------------------------
__global__ void prep_kernel(const float* __restrict__ x,
                            float4* __restrict__ coords4) {
  const int p = blockIdx.x * blockDim.x + threadIdx.x;
  if (p < N_PTS) {
    coords4[p] = make_float4(x[p * ROWF + 0], x[p * ROWF + 1],
                             x[p * ROWF + 2], 0.0f);
  }
}

// ---------------------------------------------------------------------------
// 2) FPS v13 "lean": no prune, no sort, minimal always-dirty step.
//    Rounds 7-12 showed: (a) issue-bound at 4 waves/SIMD -- instruction
//    count is the only lever (latencies overlap across waves); (b) every
//    prune variant costs more than it saves at ~10 VALU/point update.
//    Step = pk-pair d2 update (f32x2, contract off: bitwise == the scalar
//    __fmul_rn/__fadd_rn chain) + max3-tree fold + descending-j tie scan
//    (ni COMPUTED as tid+(j<<10), original order -- no sort, no ni regs) +
//    6-level DPP u64 wave fold (lane63 -> parity LDS) + 1 barrier +
//    4-level DPP u64 block fold + uniform winner load.
//    Key=(md_bits<<32)|(16383-ni): max md, tie -> lowest original index --
//    exact numpy argmax-first semantics (absmax 0 in all prior rounds).
// ---------------------------------------------------------------------------
#define REP16R(F) F(15) F(14) F(13) F(12) F(11) F(10) F(9) F(8) \
                  F(7) F(6) F(5) F(4) F(3) F(2) F(1) F(0)
#define REPP(F) F(0,0,1) F(1,2,3) F(2,4,5) F(3,6,7) \
                F(4,8,9) F(5,10,11) F(6,12,13) F(7,14,15)

__global__
__attribute__((amdgpu_flat_work_group_size(FPS_T, FPS_T)))
__attribute__((amdgpu_waves_per_eu(4, 4)))
void fps_kernel(const float4* __restrict__ coords4, float* __restrict__ out) {
#pragma clang fp contract(off)
  __shared__ u64 s_wkey[2][16];
  const int tid = threadIdx.x, lane = tid & 63, wid = tid >> 6;

#define FPS_DECL(t,a,b) f32x2 PX##t, PY##t, PZ##t; float md##a, md##b;
  REPP(FPS_DECL)
#undef FPS_DECL

#define FPS_INIT(t,a,b) {                                                  \
    const float4 va = coords4[(a << 10) + tid];                            \
    const float4 vb = coords4[(b << 10) + tid];                            \
    PX##t = (f32x2){va.x, vb.x};                                           \
    PY##t = (f32x2){va.y, vb.y};                                           \
    PZ##t = (f32x2){va.z, vb.z};                                           \
    md##a = __int_as_float(0x7f800000);                                    \
    md##b = __int_as_float(0x7f800000); }
  REPP(FPS_INIT)
#undef FPS_INIT

  const float4 q0 = coords4[0];
  float qx = q0.x, qy = q0.y, qz = q0.z;
  if (tid == 0) { out[0] = qx; out[1] = qy; out[2] = qz; }

  for (int s = 1; s < M_OUT; ++s) {
    const f32x2 QX = {qx, qx}, QY = {qy, qy}, QZ = {qz, qz};

    // ---- update all 16 points (pk pairs; IEEE RTNE per half, no fma)
#define FPS_UPD(t,a,b) {                                                   \
    const f32x2 dx = PX##t - QX;                                           \
    const f32x2 dy = PY##t - QY;                                           \
    const f32x2 dz = PZ##t - QZ;                                           \
    const f32x2 xx = dx * dx;                                              \
    const f32x2 yy = dy * dy;                                              \
    const f32x2 zz = dz * dz;                                              \
    const f32x2 ss = xx + yy;                                              \
    const f32x2 d2 = ss + zz;                                              \
    md##a = fminf(md##a, d2.x);                                            \
    md##b = fminf(md##b, d2.y); }
    REPP(FPS_UPD)
#undef FPS_UPD

    // ---- lane max via max3 tree (clang fuses fmaxf nests to v_max3_f32)
    const float a0 = fmaxf(fmaxf(md0,  md1),  md2);
    const float a1 = fmaxf(fmaxf(md3,  md4),  md5);
    const float a2 = fmaxf(fmaxf(md6,  md7),  md8);
    const float a3 = fmaxf(fmaxf(md9,  md10), md11);
    const float a4 = fmaxf(fmaxf(md12, md13), md14);
    const float b0 = fmaxf(fmaxf(a0, a1), a2);
    const float b1 = fmaxf(fmaxf(a3, a4), md15);
    const float m  = fmaxf(b0, b1);

    // ---- lowest j with md_j == m (descending chain => first match wins)
    unsigned c = 0;
#define FPS_SCAN(j) c = (md##j == m) ? (unsigned)j : c;
    REP16R(FPS_SCAN)
#undef FPS_SCAN
    const unsigned ni = (unsigned)tid + (c << 10);   // original index
    u64 k = ((u64)__float_as_uint(m) << 32) | (unsigned)(N_PTS - 1 - ni);

    // ---- wave max via DPP (lane 63 ends with full wave max)
    k = kmax_dpp<0xB1,  0xf>(k);   // quad_perm [1,0,3,2]
    k = kmax_dpp<0x4E,  0xf>(k);   // quad_perm [2,3,0,1]
    k = kmax_dpp<0x141, 0xf>(k);   // row_half_mirror (8-group)
    k = kmax_dpp<0x140, 0xf>(k);   // row_mirror      (16-group)
    k = kmax_dpp<0x142, 0xa>(k);   // row_bcast15 -> rows 1,3 (32-group)
    k = kmax_dpp<0x143, 0xc>(k);   // row_bcast31 -> rows 2,3 (64-group)

    const int par = s & 1;
    if (lane == 63) s_wkey[par][wid] = k;
    __syncthreads();                             // the ONLY barrier per step
    u64 kk = s_wkey[par][lane & 15];
    kk = kmax_dpp<0xB1,  0xf>(kk);
    kk = kmax_dpp<0x4E,  0xf>(kk);
    kk = kmax_dpp<0x141, 0xf>(kk);
    kk = kmax_dpp<0x140, 0xf>(kk);               // all lanes: block max

    const int oidx = (N_PTS - 1) - (int)(unsigned)(kk & 0xFFFFFFFFu);
    const float4 wpt = coords4[oidx];            // one uniform 16B load
    qx = wpt.x; qy = wpt.y; qz = wpt.z;
    if (tid == 0) {
      float* orow = out + (size_t)s * ROWF;
      orow[0] = qx; orow[1] = qy; orow[2] = qz;
    }
  }
}

// ---------------------------------------------------------------------------
// 3) KNN top-16 (ties -> lowest index) fused with feature max-pool.
//    One wave per query; query coords read from out rows (written by fps).
//    Packed u64 (d2_bits<<32 | idx) == lex (d2, idx).
// ---------------------------------------------------------------------------
__global__ __launch_bounds__(256)
void knn_pool_kernel(const float* __restrict__ x,
                     const float4* __restrict__ coords4,
                     float* __restrict__ out) {
  const int lane = threadIdx.x & 63;
  const int q = blockIdx.x * 4 + (threadIdx.x >> 6);

  const float qx = out[(size_t)q * ROWF + 0];
  const float qy = out[(size_t)q * ROWF + 1];
  const float qz = out[(size_t)q * ROWF + 2];

  u64 h[KNN];
#pragma unroll
  for (int k = 0; k < KNN; ++k) h[k] = ~0ULL;

  for (int c = lane; c < N_PTS; c += 64) {
    const float4 v = coords4[c];                 // coalesced 16B
    const float dx = v.x - qx, dy = v.y - qy, dz = v.z - qz;
    const float d2 = __fadd_rn(__fadd_rn(__fmul_rn(dx, dx), __fmul_rn(dy, dy)),
                               __fmul_rn(dz, dz));
    const u64 e = ((u64)__float_as_uint(d2) << 32) | (unsigned)c;
    if (e < h[KNN - 1]) {
#pragma unroll
      for (int k = KNN - 1; k >= 1; --k) {
        const u64 prev = h[k - 1];
        h[k] = (e < prev) ? prev : ((e < h[k]) ? e : h[k]);
      }
      h[0] = (e < h[0]) ? e : h[0];
    }
  }

  int nbr[KNN];
#pragma unroll
  for (int rr = 0; rr < KNN; ++rr) {
    u64 best = h[0];
#pragma unroll
    for (int off = 32; off; off >>= 1) {
      const u64 o = __shfl_xor(best, off);
      best = (o < best) ? o : best;
    }
    nbr[rr] = (int)(unsigned)(best & 0xffffffffULL);
    if (h[0] == best) {
#pragma unroll
      for (int k = 0; k < KNN - 1; ++k) h[k] = h[k + 1];
      h[KNN - 1] = ~0ULL;
    }
  }

  float a0 = __int_as_float(0xff800000), a1 = a0;
#pragma unroll
  for (int rr = 0; rr < KNN; ++rr) {
    const float* row = x + (size_t)nbr[rr] * ROWF + 3;
    a0 = fmaxf(a0, row[lane]);
    a1 = fmaxf(a1, row[lane + 64]);
  }
  float* orow = out + (size_t)q * ROWF + 3;
  orow[lane] = a0;
  orow[lane + 64] = a1;
}

extern "C" void kernel_launch(void* const* d_in, const int* in_sizes, int n_in,
                              void* d_out, int out_size, void* d_ws, size_t ws_size,
                              hipStream_t stream) {
  const float* x = (const float*)d_in[0];
  float* out = (float*)d_out;

  float4* coords4 = (float4*)d_ws;          // N float4 (256 KB)

  hipLaunchKernelGGL(prep_kernel, dim3(64), dim3(256), 0, stream, x, coords4);
  hipLaunchKernelGGL(fps_kernel, dim3(1), dim3(FPS_T), 0, stream, coords4, out);
  hipLaunchKernelGGL(knn_pool_kernel, dim3(M_OUT / 4), dim3(256), 0, stream,
                     x, coords4, out);
}

// Round 14
// 6649.282 us; speedup vs baseline: 1.2656x; 1.0003x over previous
//
#include <hip/hip_runtime.h>

#define N_PTS 16384
#define ROWF  131        // 3 coords + 128 features
#define M_OUT 4096       // N / POOL
#define KNN   16
#define FPS_T 1024       // fps threads (16 waves)

typedef unsigned long long u64;
typedef float f32x2 __attribute__((ext_vector_type(2)));

// u64 max-combine with a DPP-moved partner (VALU pipe, ~2cyc vs ~50cyc shfl).
// Verified on-device in rounds 10-12 (absmax 0 throughout).
template <int CTRL, int ROW_MASK>
__device__ __forceinline__ u64 kmax_dpp(u64 k) {
  const int lo = (int)(unsigned)k, hi = (int)(unsigned)(k >> 32);
  const int nlo = __builtin_amdgcn_update_dpp(lo, lo, CTRL, ROW_MASK, 0xf, false);
  const int nhi = __builtin_amdgcn_update_dpp(hi, hi, CTRL, ROW_MASK, 0xf, false);
  const u64 nk = ((u64)(unsigned)nhi << 32) | (unsigned)nlo;
  return nk > k ? nk : k;
}

// ---------------------------------------------------------------------------
// 1) Extract coords into packed float4 (x,y,z,0), original index order.
// ---------------------------------------------------------------------------
__global__ void prep_kernel(const float* __restrict__ x,
                            float4* __restrict__ coords4) {
  const int p = blockIdx.x * blockDim.x + threadIdx.x;
  if (p < N_PTS) {
    coords4[p] = make_float4(x[p * ROWF + 0], x[p * ROWF + 1],
                             x[p * ROWF + 2], 0.0f);
  }
}

// ---------------------------------------------------------------------------
// 2) FPS v13 "lean": no prune, no sort, minimal always-dirty step.
//    Rounds 7-12 showed: (a) issue-bound at 4 waves/SIMD -- instruction
//    count is the only lever (latencies overlap across waves); (b) every
//    prune variant costs more than it saves at ~10 VALU/point update.
//    Step = pk-pair d2 update (f32x2, contract off: bitwise == the scalar
//    __fmul_rn/__fadd_rn chain) + max3-tree fold + descending-j tie scan
//    (ni COMPUTED as tid+(j<<10), original order -- no sort, no ni regs) +
//    6-level DPP u64 wave fold (lane63 -> parity LDS) + 1 barrier +
//    4-level DPP u64 block fold + uniform winner load.
//    Key=(md_bits<<32)|(16383-ni): max md, tie -> lowest original index --
//    exact numpy argmax-first semantics (absmax 0 in all prior rounds).
// ---------------------------------------------------------------------------
#define REP16R(F) F(15) F(14) F(13) F(12) F(11) F(10) F(9) F(8) \
                  F(7) F(6) F(5) F(4) F(3) F(2) F(1) F(0)
#define REPP(F) F(0,0,1) F(1,2,3) F(2,4,5) F(3,6,7) \
                F(4,8,9) F(5,10,11) F(6,12,13) F(7,14,15)

__global__
__attribute__((amdgpu_flat_work_group_size(FPS_T, FPS_T)))
__attribute__((amdgpu_waves_per_eu(4, 4)))
void fps_kernel(const float4* __restrict__ coords4, float* __restrict__ out) {
#pragma clang fp contract(off)
  __shared__ u64 s_wkey[2][16];
  const int tid = threadIdx.x, lane = tid & 63, wid = tid >> 6;

#define FPS_DECL(t,a,b) f32x2 PX##t, PY##t, PZ##t; float md##a, md##b;
  REPP(FPS_DECL)
#undef FPS_DECL

#define FPS_INIT(t,a,b) {                                                  \
    const float4 va = coords4[(a << 10) + tid];                            \
    const float4 vb = coords4[(b << 10) + tid];                            \
    PX##t = (f32x2){va.x, vb.x};                                           \
    PY##t = (f32x2){va.y, vb.y};                                           \
    PZ##t = (f32x2){va.z, vb.z};                                           \
    md##a = __int_as_float(0x7f800000);                                    \
    md##b = __int_as_float(0x7f800000); }
  REPP(FPS_INIT)
#undef FPS_INIT

  const float4 q0 = coords4[0];
  float qx = q0.x, qy = q0.y, qz = q0.z;
  if (tid == 0) { out[0] = qx; out[1] = qy; out[2] = qz; }

  for (int s = 1; s < M_OUT; ++s) {
    const f32x2 QX = {qx, qx}, QY = {qy, qy}, QZ = {qz, qz};

    // ---- update all 16 points (pk pairs; IEEE RTNE per half, no fma)
#define FPS_UPD(t,a,b) {                                                   \
    const f32x2 dx = PX##t - QX;                                           \
    const f32x2 dy = PY##t - QY;                                           \
    const f32x2 dz = PZ##t - QZ;                                           \
    const f32x2 xx = dx * dx;                                              \
    const f32x2 yy = dy * dy;                                              \
    const f32x2 zz = dz * dz;                                              \
    const f32x2 ss = xx + yy;                                              \
    const f32x2 d2 = ss + zz;                                              \
    md##a = fminf(md##a, d2.x);                                            \
    md##b = fminf(md##b, d2.y); }
    REPP(FPS_UPD)
#undef FPS_UPD

    // ---- lane max via max3 tree (clang fuses fmaxf nests to v_max3_f32)
    const float a0 = fmaxf(fmaxf(md0,  md1),  md2);
    const float a1 = fmaxf(fmaxf(md3,  md4),  md5);
    const float a2 = fmaxf(fmaxf(md6,  md7),  md8);
    const float a3 = fmaxf(fmaxf(md9,  md10), md11);
    const float a4 = fmaxf(fmaxf(md12, md13), md14);
    const float b0 = fmaxf(fmaxf(a0, a1), a2);
    const float b1 = fmaxf(fmaxf(a3, a4), md15);
    const float m  = fmaxf(b0, b1);

    // ---- lowest j with md_j == m (descending chain => first match wins)
    unsigned c = 0;
#define FPS_SCAN(j) c = (md##j == m) ? (unsigned)j : c;
    REP16R(FPS_SCAN)
#undef FPS_SCAN
    const unsigned ni = (unsigned)tid + (c << 10);   // original index
    u64 k = ((u64)__float_as_uint(m) << 32) | (unsigned)(N_PTS - 1 - ni);

    // ---- wave max via DPP (lane 63 ends with full wave max)
    k = kmax_dpp<0xB1,  0xf>(k);   // quad_perm [1,0,3,2]
    k = kmax_dpp<0x4E,  0xf>(k);   // quad_perm [2,3,0,1]
    k = kmax_dpp<0x141, 0xf>(k);   // row_half_mirror (8-group)
    k = kmax_dpp<0x140, 0xf>(k);   // row_mirror      (16-group)
    k = kmax_dpp<0x142, 0xa>(k);   // row_bcast15 -> rows 1,3 (32-group)
    k = kmax_dpp<0x143, 0xc>(k);   // row_bcast31 -> rows 2,3 (64-group)

    const int par = s & 1;
    if (lane == 63) s_wkey[par][wid] = k;
    __syncthreads();                             // the ONLY barrier per step
    u64 kk = s_wkey[par][lane & 15];
    kk = kmax_dpp<0xB1,  0xf>(kk);
    kk = kmax_dpp<0x4E,  0xf>(kk);
    kk = kmax_dpp<0x141, 0xf>(kk);
    kk = kmax_dpp<0x140, 0xf>(kk);               // all lanes: block max

    const int oidx = (N_PTS - 1) - (int)(unsigned)(kk & 0xFFFFFFFFu);
    const float4 wpt = coords4[oidx];            // one uniform 16B load
    qx = wpt.x; qy = wpt.y; qz = wpt.z;
    if (tid == 0) {
      float* orow = out + (size_t)s * ROWF;
      orow[0] = qx; orow[1] = qy; orow[2] = qz;
    }
  }
}

// ---------------------------------------------------------------------------
// 3) KNN top-16 (ties -> lowest index) fused with feature max-pool.
//    One wave per query; query coords read from out rows (written by fps).
//    Packed u64 (d2_bits<<32 | idx) == lex (d2, idx).
// ---------------------------------------------------------------------------
__global__ __launch_bounds__(256)
void knn_pool_kernel(const float* __restrict__ x,
                     const float4* __restrict__ coords4,
                     float* __restrict__ out) {
  const int lane = threadIdx.x & 63;
  const int q = blockIdx.x * 4 + (threadIdx.x >> 6);

  const float qx = out[(size_t)q * ROWF + 0];
  const float qy = out[(size_t)q * ROWF + 1];
  const float qz = out[(size_t)q * ROWF + 2];

  u64 h[KNN];
#pragma unroll
  for (int k = 0; k < KNN; ++k) h[k] = ~0ULL;

  for (int c = lane; c < N_PTS; c += 64) {
    const float4 v = coords4[c];                 // coalesced 16B
    const float dx = v.x - qx, dy = v.y - qy, dz = v.z - qz;
    const float d2 = __fadd_rn(__fadd_rn(__fmul_rn(dx, dx), __fmul_rn(dy, dy)),
                               __fmul_rn(dz, dz));
    const u64 e = ((u64)__float_as_uint(d2) << 32) | (unsigned)c;
    if (e < h[KNN - 1]) {
#pragma unroll
      for (int k = KNN - 1; k >= 1; --k) {
        const u64 prev = h[k - 1];
        h[k] = (e < prev) ? prev : ((e < h[k]) ? e : h[k]);
      }
      h[0] = (e < h[0]) ? e : h[0];
    }
  }

  int nbr[KNN];
#pragma unroll
  for (int rr = 0; rr < KNN; ++rr) {
    u64 best = h[0];
#pragma unroll
    for (int off = 32; off; off >>= 1) {
      const u64 o = __shfl_xor(best, off);
      best = (o < best) ? o : best;
    }
    nbr[rr] = (int)(unsigned)(best & 0xffffffffULL);
    if (h[0] == best) {
#pragma unroll
      for (int k = 0; k < KNN - 1; ++k) h[k] = h[k + 1];
      h[KNN - 1] = ~0ULL;
    }
  }

  float a0 = __int_as_float(0xff800000), a1 = a0;
#pragma unroll
  for (int rr = 0; rr < KNN; ++rr) {
    const float* row = x + (size_t)nbr[rr] * ROWF + 3;
    a0 = fmaxf(a0, row[lane]);
    a1 = fmaxf(a1, row[lane + 64]);
  }
  float* orow = out + (size_t)q * ROWF + 3;
  orow[lane] = a0;
  orow[lane + 64] = a1;
}

extern "C" void kernel_launch(void* const* d_in, const int* in_sizes, int n_in,
                              void* d_out, int out_size, void* d_ws, size_t ws_size,
                              hipStream_t stream) {
  const float* x = (const float*)d_in[0];
  float* out = (float*)d_out;

  float4* coords4 = (float4*)d_ws;          // N float4 (256 KB)

  hipLaunchKernelGGL(prep_kernel, dim3(64), dim3(256), 0, stream, x, coords4);
  hipLaunchKernelGGL(fps_kernel, dim3(1), dim3(FPS_T), 0, stream, coords4, out);
  hipLaunchKernelGGL(knn_pool_kernel, dim3(M_OUT / 4), dim3(256), 0, stream,
                     x, coords4, out);
}

// Round 15
// 6648.407 us; speedup vs baseline: 1.2658x; 1.0001x over previous
//
#include <hip/hip_runtime.h>

#define N_PTS 16384
#define ROWF  131        // 3 coords + 128 features
#define M_OUT 4096       // N / POOL
#define KNN   16
#define FPS_T 1024       // fps threads (16 waves)

typedef unsigned long long u64;
typedef float f32x2 __attribute__((ext_vector_type(2)));

// u64 max-combine with a DPP-moved partner (VALU pipe, ~2cyc vs ~50cyc shfl).
// Verified on-device in rounds 10-12 (absmax 0 throughout).
template <int CTRL, int ROW_MASK>
__device__ __forceinline__ u64 kmax_dpp(u64 k) {
  const int lo = (int)(unsigned)k, hi = (int)(unsigned)(k >> 32);
  const int nlo = __builtin_amdgcn_update_dpp(lo, lo, CTRL, ROW_MASK, 0xf, false);
  const int nhi = __builtin_amdgcn_update_dpp(hi, hi, CTRL, ROW_MASK, 0xf, false);
  const u64 nk = ((u64)(unsigned)nhi << 32) | (unsigned)nlo;
  return nk > k ? nk : k;
}

// ---------------------------------------------------------------------------
// 1) Extract coords into packed float4 (x,y,z,0), original index order.
// ---------------------------------------------------------------------------
__global__ void prep_kernel(const float* __restrict__ x,
                            float4* __restrict__ coords4) {
  const int p = blockIdx.x * blockDim.x + threadIdx.x;
  if (p < N_PTS) {
    coords4[p] = make_float4(x[p * ROWF + 0], x[p * ROWF + 1],
                             x[p * ROWF + 2], 0.0f);
  }
}

// ---------------------------------------------------------------------------
// 2) FPS v13 "lean": no prune, no sort, minimal always-dirty step.
//    Rounds 7-12 showed: (a) issue-bound at 4 waves/SIMD -- instruction
//    count is the only lever (latencies overlap across waves); (b) every
//    prune variant costs more than it saves at ~10 VALU/point update.
//    Step = pk-pair d2 update (f32x2, contract off: bitwise == the scalar
//    __fmul_rn/__fadd_rn chain) + max3-tree fold + descending-j tie scan
//    (ni COMPUTED as tid+(j<<10), original order -- no sort, no ni regs) +
//    6-level DPP u64 wave fold (lane63 -> parity LDS) + 1 barrier +
//    4-level DPP u64 block fold + uniform winner load.
//    Key=(md_bits<<32)|(16383-ni): max md, tie -> lowest original index --
//    exact numpy argmax-first semantics (absmax 0 in all prior rounds).
// ---------------------------------------------------------------------------
#define REP16R(F) F(15) F(14) F(13) F(12) F(11) F(10) F(9) F(8) \
                  F(7) F(6) F(5) F(4) F(3) F(2) F(1) F(0)
#define REPP(F) F(0,0,1) F(1,2,3) F(2,4,5) F(3,6,7) \
                F(4,8,9) F(5,10,11) F(6,12,13) F(7,14,15)

__global__
__attribute__((amdgpu_flat_work_group_size(FPS_T, FPS_T)))
__attribute__((amdgpu_waves_per_eu(4, 4)))
void fps_kernel(const float4* __restrict__ coords4, float* __restrict__ out) {
#pragma clang fp contract(off)
  __shared__ u64 s_wkey[2][16];
  const int tid = threadIdx.x, lane = tid & 63, wid = tid >> 6;

#define FPS_DECL(t,a,b) f32x2 PX##t, PY##t, PZ##t; float md##a, md##b;
  REPP(FPS_DECL)
#undef FPS_DECL

#define FPS_INIT(t,a,b) {                                                  \
    const float4 va = coords4[(a << 10) + tid];                            \
    const float4 vb = coords4[(b << 10) + tid];                            \
    PX##t = (f32x2){va.x, vb.x};                                           \
    PY##t = (f32x2){va.y, vb.y};                                           \
    PZ##t = (f32x2){va.z, vb.z};                                           \
    md##a = __int_as_float(0x7f800000);                                    \
    md##b = __int_as_float(0x7f800000); }
  REPP(FPS_INIT)
#undef FPS_INIT

  const float4 q0 = coords4[0];
  float qx = q0.x, qy = q0.y, qz = q0.z;
  if (tid == 0) { out[0] = qx; out[1] = qy; out[2] = qz; }

  for (int s = 1; s < M_OUT; ++s) {
    const f32x2 QX = {qx, qx}, QY = {qy, qy}, QZ = {qz, qz};

    // ---- update all 16 points (pk pairs; IEEE RTNE per half, no fma)
#define FPS_UPD(t,a,b) {                                                   \
    const f32x2 dx = PX##t - QX;                                           \
    const f32x2 dy = PY##t - QY;                                           \
    const f32x2 dz = PZ##t - QZ;                                           \
    const f32x2 xx = dx * dx;                                              \
    const f32x2 yy = dy * dy;                                              \
    const f32x2 zz = dz * dz;                                              \
    const f32x2 ss = xx + yy;                                              \
    const f32x2 d2 = ss + zz;                                              \
    md##a = fminf(md##a, d2.x);                                            \
    md##b = fminf(md##b, d2.y); }
    REPP(FPS_UPD)
#undef FPS_UPD

    // ---- lane max via max3 tree (clang fuses fmaxf nests to v_max3_f32)
    const float a0 = fmaxf(fmaxf(md0,  md1),  md2);
    const float a1 = fmaxf(fmaxf(md3,  md4),  md5);
    const float a2 = fmaxf(fmaxf(md6,  md7),  md8);
    const float a3 = fmaxf(fmaxf(md9,  md10), md11);
    const float a4 = fmaxf(fmaxf(md12, md13), md14);
    const float b0 = fmaxf(fmaxf(a0, a1), a2);
    const float b1 = fmaxf(fmaxf(a3, a4), md15);
    const float m  = fmaxf(b0, b1);

    // ---- lowest j with md_j == m (descending chain => first match wins)
    unsigned c = 0;
#define FPS_SCAN(j) c = (md##j == m) ? (unsigned)j : c;
    REP16R(FPS_SCAN)
#undef FPS_SCAN
    const unsigned ni = (unsigned)tid + (c << 10);   // original index
    u64 k = ((u64)__float_as_uint(m) << 32) | (unsigned)(N_PTS - 1 - ni);

    // ---- wave max via DPP (lane 63 ends with full wave max)
    k = kmax_dpp<0xB1,  0xf>(k);   // quad_perm [1,0,3,2]
    k = kmax_dpp<0x4E,  0xf>(k);   // quad_perm [2,3,0,1]
    k = kmax_dpp<0x141, 0xf>(k);   // row_half_mirror (8-group)
    k = kmax_dpp<0x140, 0xf>(k);   // row_mirror      (16-group)
    k = kmax_dpp<0x142, 0xa>(k);   // row_bcast15 -> rows 1,3 (32-group)
    k = kmax_dpp<0x143, 0xc>(k);   // row_bcast31 -> rows 2,3 (64-group)

    const int par = s & 1;
    if (lane == 63) s_wkey[par][wid] = k;
    __syncthreads();                             // the ONLY barrier per step
    u64 kk = s_wkey[par][lane & 15];
    kk = kmax_dpp<0xB1,  0xf>(kk);
    kk = kmax_dpp<0x4E,  0xf>(kk);
    kk = kmax_dpp<0x141, 0xf>(kk);
    kk = kmax_dpp<0x140, 0xf>(kk);               // all lanes: block max

    const int oidx = (N_PTS - 1) - (int)(unsigned)(kk & 0xFFFFFFFFu);
    const float4 wpt = coords4[oidx];            // one uniform 16B load
    qx = wpt.x; qy = wpt.y; qz = wpt.z;
    if (tid == 0) {
      float* orow = out + (size_t)s * ROWF;
      orow[0] = qx; orow[1] = qy; orow[2] = qz;
    }
  }
}

// ---------------------------------------------------------------------------
// 3) KNN top-16 (ties -> lowest index) fused with feature max-pool.
//    One wave per query; query coords read from out rows (written by fps).
//    Packed u64 (d2_bits<<32 | idx) == lex (d2, idx).
// ---------------------------------------------------------------------------
__global__ __launch_bounds__(256)
void knn_pool_kernel(const float* __restrict__ x,
                     const float4* __restrict__ coords4,
                     float* __restrict__ out) {
  const int lane = threadIdx.x & 63;
  const int q = blockIdx.x * 4 + (threadIdx.x >> 6);

  const float qx = out[(size_t)q * ROWF + 0];
  const float qy = out[(size_t)q * ROWF + 1];
  const float qz = out[(size_t)q * ROWF + 2];

  u64 h[KNN];
#pragma unroll
  for (int k = 0; k < KNN; ++k) h[k] = ~0ULL;

  for (int c = lane; c < N_PTS; c += 64) {
    const float4 v = coords4[c];                 // coalesced 16B
    const float dx = v.x - qx, dy = v.y - qy, dz = v.z - qz;
    const float d2 = __fadd_rn(__fadd_rn(__fmul_rn(dx, dx), __fmul_rn(dy, dy)),
                               __fmul_rn(dz, dz));
    const u64 e = ((u64)__float_as_uint(d2) << 32) | (unsigned)c;
    if (e < h[KNN - 1]) {
#pragma unroll
      for (int k = KNN - 1; k >= 1; --k) {
        const u64 prev = h[k - 1];
        h[k] = (e < prev) ? prev : ((e < h[k]) ? e : h[k]);
      }
      h[0] = (e < h[0]) ? e : h[0];
    }
  }

  int nbr[KNN];
#pragma unroll
  for (int rr = 0; rr < KNN; ++rr) {
    u64 best = h[0];
#pragma unroll
    for (int off = 32; off; off >>= 1) {
      const u64 o = __shfl_xor(best, off);
      best = (o < best) ? o : best;
    }
    nbr[rr] = (int)(unsigned)(best & 0xffffffffULL);
    if (h[0] == best) {
#pragma unroll
      for (int k = 0; k < KNN - 1; ++k) h[k] = h[k + 1];
      h[KNN - 1] = ~0ULL;
    }
  }

  float a0 = __int_as_float(0xff800000), a1 = a0;
#pragma unroll
  for (int rr = 0; rr < KNN; ++rr) {
    const float* row = x + (size_t)nbr[rr] * ROWF + 3;
    a0 = fmaxf(a0, row[lane]);
    a1 = fmaxf(a1, row[lane + 64]);
  }
  float* orow = out + (size_t)q * ROWF + 3;
  orow[lane] = a0;
  orow[lane + 64] = a1;
}

extern "C" void kernel_launch(void* const* d_in, const int* in_sizes, int n_in,
                              void* d_out, int out_size, void* d_ws, size_t ws_size,
                              hipStream_t stream) {
  const float* x = (const float*)d_in[0];
  float* out = (float*)d_out;

  float4* coords4 = (float4*)d_ws;          // N float4 (256 KB)

  hipLaunchKernelGGL(prep_kernel, dim3(64), dim3(256), 0, stream, x, coords4);
  hipLaunchKernelGGL(fps_kernel, dim3(1), dim3(FPS_T), 0, stream, coords4, out);
  hipLaunchKernelGGL(knn_pool_kernel, dim3(M_OUT / 4), dim3(256), 0, stream,
                     x, coords4, out);
}